// Round 3
// baseline (8556.863 us; speedup 1.0000x reference)
//
#include <hip/hip_runtime.h>
#include <math.h>

#define NN 100000
#define M1 200000
#define M2 100000
#define TILES 1563  // ceil(NN/64)

__device__ __forceinline__ float bc(float x, int l) {
  return __int_as_float(__builtin_amdgcn_readlane(__float_as_int(x), l));
}

__device__ __forceinline__ float wred(float x) {
  x += __shfl_xor(x, 1, 64);
  x += __shfl_xor(x, 2, 64);
  x += __shfl_xor(x, 4, 64);
  x += __shfl_xor(x, 8, 64);
  x += __shfl_xor(x, 16, 64);
  x += __shfl_xor(x, 32, 64);
  return x;
}

// branch-free tanh: 1 - 2/(e^{2x}+1); saturates to +-1 correctly, ~1e-6 err.
__device__ __forceinline__ float tanh_fast(float x) {
  float e = __expf(2.f * x);
  return 1.f - 2.f / (e + 1.f);
}

__global__ void k_zero(float* p) { p[blockIdx.x * 256 + threadIdx.x] = 0.f; }

// ---- A1: per-table-row (dot = att_hi . row, asum = ||row||_1) ----
__global__ void __launch_bounds__(256) k_tab_pairs(
    const float* __restrict__ tab, const float* __restrict__ atth,
    float2* __restrict__ out, int M) {
  int r = blockIdx.x * 256 + threadIdx.x;
  int stride = gridDim.x * 256;
  for (; r < M; r += stride) {
    const float4* row = (const float4*)(tab + (size_t)r * 64);
    float dot = 0.f, asum = 0.f;
#pragma unroll
    for (int k = 0; k < 16; k++) {
      float4 v = row[k];
      float4 a = *(const float4*)(atth + 4 * k);  // uniform -> s_load
      dot = fmaf(v.x, a.x, dot); dot = fmaf(v.y, a.y, dot);
      dot = fmaf(v.z, a.z, dot); dot = fmaf(v.w, a.w, dot);
      asum += fabsf(v.x) + fabsf(v.y) + fabsf(v.z) + fabsf(v.w);
    }
    out[r] = make_float2(dot, asum);
  }
}

// ---- A2: per-node pairs, 4-way split (seg = which of the 4 (W,b,att) combos) ----
__global__ void __launch_bounds__(256) k_node_pairs4(
    const float* __restrict__ h0, const float* __restrict__ rf0,
    const float* __restrict__ W0, const float* __restrict__ b0, const float* __restrict__ a0,
    const float* __restrict__ W1, const float* __restrict__ b1, const float* __restrict__ a1,
    const float* __restrict__ W2, const float* __restrict__ b2, const float* __restrict__ a2,
    const float* __restrict__ W3, const float* __restrict__ b3, const float* __restrict__ a3,
    float2* __restrict__ o0, float2* __restrict__ o1,
    float2* __restrict__ o2, float2* __restrict__ o3) {
  int seg = blockIdx.x & 3;
  int n = (blockIdx.x >> 2) * 256 + threadIdx.x;
  if (n >= NN) return;
  const float* X = (seg < 2) ? h0 : rf0;
  const float* W = (seg == 0) ? W0 : (seg == 1) ? W1 : (seg == 2) ? W2 : W3;
  const float* b = (seg == 0) ? b0 : (seg == 1) ? b1 : (seg == 2) ? b2 : b3;
  const float* a = (seg == 0) ? a0 : (seg == 1) ? a1 : (seg == 2) ? a2 : a3;
  float2* o      = (seg == 0) ? o0 : (seg == 1) ? o1 : (seg == 2) ? o2 : o3;

  float x[64];
  const float4* row = (const float4*)(X + (size_t)n * 64);
#pragma unroll
  for (int k = 0; k < 16; k++) {
    float4 v = row[k];
    x[4 * k] = v.x; x[4 * k + 1] = v.y; x[4 * k + 2] = v.z; x[4 * k + 3] = v.w;
  }
  float dot = 0.f, asum = 0.f;
  for (int d = 0; d < 64; d++) {  // rolled; W/b/a uniform -> scalar loads
    const float4* wr = (const float4*)(W + d * 64);
    float r0 = b[d], r1 = 0.f, r2 = 0.f, r3 = 0.f;
#pragma unroll
    for (int k = 0; k < 16; k += 4) {
      float4 wA = wr[k], wB = wr[k + 1], wC = wr[k + 2], wD = wr[k + 3];
      r0 = fmaf(wA.x, x[4*k+0],  r0); r0 = fmaf(wA.y, x[4*k+1],  r0);
      r0 = fmaf(wA.z, x[4*k+2],  r0); r0 = fmaf(wA.w, x[4*k+3],  r0);
      r1 = fmaf(wB.x, x[4*k+4],  r1); r1 = fmaf(wB.y, x[4*k+5],  r1);
      r1 = fmaf(wB.z, x[4*k+6],  r1); r1 = fmaf(wB.w, x[4*k+7],  r1);
      r2 = fmaf(wC.x, x[4*k+8],  r2); r2 = fmaf(wC.y, x[4*k+9],  r2);
      r2 = fmaf(wC.z, x[4*k+10], r2); r2 = fmaf(wC.w, x[4*k+11], r2);
      r3 = fmaf(wD.x, x[4*k+12], r3); r3 = fmaf(wD.y, x[4*k+13], r3);
      r3 = fmaf(wD.z, x[4*k+14], r3); r3 = fmaf(wD.w, x[4*k+15], r3);
    }
    float r = (r0 + r1) + (r2 + r3);
    dot = fmaf(a[d], r, dot);
    asum += fabsf(r);
  }
  o[n] = make_float2(dot, asum);
}

// ---- B: attend. wave = node, lane = dim. Scores on lanes 0..15, gathers coalesced. ----
__global__ void __launch_bounds__(256) k_attend(
    const int* __restrict__ nei,
    const float* __restrict__ tabA, const float* __restrict__ tabR,
    const float2* __restrict__ tpA, const float2* __restrict__ tpR,
    const float2* __restrict__ npA, const float2* __restrict__ npR,
    float* __restrict__ outA, float* __restrict__ outR) {
  int lane = threadIdx.x & 63, wid = threadIdx.x >> 6;
  for (int n = blockIdx.x * 4 + wid; n < NN; n += gridDim.x * 4) {
    const int* nb = nei + (size_t)n * 8;
    int myidx = nb[lane & 7];
    float2 pnA = npA[n], pnR = npR[n];           // uniform
    float2 pn = (lane & 8) ? pnR : pnA;
    const float2* tpp = (lane & 8) ? tpR : tpA;
    float2 tp = tpp[myidx];
    float t = (pn.x + tp.x) / fmaxf(pn.y + tp.y, 1e-12f);
    t = (t >= 0.f) ? t : 0.01f * t;              // leaky_relu(0.01)
    float m = t;
    m = fmaxf(m, __shfl_xor(m, 1, 64));
    m = fmaxf(m, __shfl_xor(m, 2, 64));
    m = fmaxf(m, __shfl_xor(m, 4, 64));
    float u = expf(t - m);
    float den = u;
    den += __shfl_xor(den, 1, 64);
    den += __shfl_xor(den, 2, 64);
    den += __shfl_xor(den, 4, 64);
    float w = u / den;                           // lanes 0..7: A weights, 8..15: R weights
    int is[8];
#pragma unroll
    for (int s = 0; s < 8; s++) is[s] = nb[s];   // uniform -> s_load
    float vA[8], vR[8];
#pragma unroll
    for (int s = 0; s < 8; s++) {
      vA[s] = tabA[(size_t)is[s] * 64 + lane];
      vR[s] = tabR[(size_t)is[s] * 64 + lane];
    }
    float eA = 0.f, eR = 0.f;
#pragma unroll
    for (int s = 0; s < 8; s++) {
      eA = fmaf(bc(w, s), vA[s], eA);
      eR = fmaf(bc(w, 8 + s), vR[s], eR);
    }
    outA[(size_t)n * 64 + lane] = eA;
    outR[(size_t)n * 64 + lane] = eR;
  }
}

// ---- C (fast): out[d] += sum_n tanh(W[d,:].E[n,:] + b[d]).
// lane = node, per-lane acc[d] in VGPRs, W streamed via scalar loads,
// wave-level reduction ONCE at the end.
__global__ void __launch_bounds__(256) k_colsum_fast(
    const float* __restrict__ E, const float* __restrict__ W,
    const float* __restrict__ bias, float* __restrict__ out) {
  int lane = threadIdx.x & 63;
  int wv = (blockIdx.x << 2) + (threadIdx.x >> 6);
  int nw = gridDim.x << 2;
  float acc[64];
#pragma unroll
  for (int d = 0; d < 64; d++) acc[d] = 0.f;
  for (int t = wv; t < TILES; t += nw) {
    int n = t * 64 + lane;
    bool valid = n < NN;
    const float4* row = (const float4*)(E + (size_t)(valid ? n : 0) * 64);
    float x[64];
#pragma unroll
    for (int k = 0; k < 16; k++) {
      float4 v = row[k];
      x[4 * k] = v.x; x[4 * k + 1] = v.y; x[4 * k + 2] = v.z; x[4 * k + 3] = v.w;
    }
    float vm = valid ? 1.f : 0.f;
#pragma unroll
    for (int d = 0; d < 64; d++) {
      const float4* wr = (const float4*)(W + d * 64);  // uniform -> s_load
      float r0 = bias[d], r1 = 0.f, r2 = 0.f, r3 = 0.f;
#pragma unroll
      for (int k = 0; k < 16; k += 4) {
        float4 wA = wr[k], wB = wr[k + 1], wC = wr[k + 2], wD = wr[k + 3];
        r0 = fmaf(wA.x, x[4*k+0],  r0); r0 = fmaf(wA.y, x[4*k+1],  r0);
        r0 = fmaf(wA.z, x[4*k+2],  r0); r0 = fmaf(wA.w, x[4*k+3],  r0);
        r1 = fmaf(wB.x, x[4*k+4],  r1); r1 = fmaf(wB.y, x[4*k+5],  r1);
        r1 = fmaf(wB.z, x[4*k+6],  r1); r1 = fmaf(wB.w, x[4*k+7],  r1);
        r2 = fmaf(wC.x, x[4*k+8],  r2); r2 = fmaf(wC.y, x[4*k+9],  r2);
        r2 = fmaf(wC.z, x[4*k+10], r2); r2 = fmaf(wC.w, x[4*k+11], r2);
        r3 = fmaf(wD.x, x[4*k+12], r3); r3 = fmaf(wD.y, x[4*k+13], r3);
        r3 = fmaf(wD.z, x[4*k+14], r3); r3 = fmaf(wD.w, x[4*k+15], r3);
      }
      float r = (r0 + r1) + (r2 + r3);
      acc[d] += vm * tanh_fast(r);
    }
  }
  float keep = 0.f;
#pragma unroll
  for (int d = 0; d < 64; d++) {
    float s = wred(acc[d]);
    if (lane == d) keep = s;
  }
  atomicAdd(&out[lane], keep);
}

__global__ void k_ibeta(const float* __restrict__ sums,
                        const float* __restrict__ aggatt0,
                        const float* __restrict__ aggatt1,
                        float* __restrict__ betas) {
  int lane = threadIdx.x;  // 64 threads
  float invN = 1.f / (float)NN;
#pragma unroll
  for (int r = 0; r < 2; r++) {
    const float* aggatt = r ? aggatt1 : aggatt0;
    float ga = wred(aggatt[lane] * sums[r * 128 + lane] * invN);
    float gb = wred(aggatt[lane] * sums[r * 128 + 64 + lane] * invN);
    float mm = fmaxf(ga, gb);
    float ea = expf(ga - mm), eb = expf(gb - mm);
    if (lane == 0) {
      betas[2 * r] = ea / (ea + eb);
      betas[2 * r + 1] = eb / (ea + eb);
    }
  }
}

__global__ void __launch_bounds__(256) k_mix_elem(
    float4* __restrict__ pA0, const float4* __restrict__ pR0,
    float4* __restrict__ pA1, const float4* __restrict__ pR1,
    const float* __restrict__ betas) {
  float ba0 = betas[0], bb0 = betas[1], ba1 = betas[2], bb1 = betas[3];
  int total = NN * 64 / 4;
  for (int i = blockIdx.x * blockDim.x + threadIdx.x; i < total; i += gridDim.x * blockDim.x) {
    float4 a = pA0[i], b = pR0[i];
    float4 o;
    o.x = ba0 * a.x + bb0 * b.x; o.y = ba0 * a.y + bb0 * b.y;
    o.z = ba0 * a.z + bb0 * b.z; o.w = ba0 * a.w + bb0 * b.w;
    o.x = (o.x > 0.f) ? o.x : expm1f(o.x);
    o.y = (o.y > 0.f) ? o.y : expm1f(o.y);
    o.z = (o.z > 0.f) ? o.z : expm1f(o.z);
    o.w = (o.w > 0.f) ? o.w : expm1f(o.w);
    pA0[i] = o;
    a = pA1[i]; b = pR1[i];
    o.x = ba1 * a.x + bb1 * b.x; o.y = ba1 * a.y + bb1 * b.y;
    o.z = ba1 * a.z + bb1 * b.z; o.w = ba1 * a.w + bb1 * b.w;
    o.x = (o.x > 0.f) ? o.x : expm1f(o.x);
    o.y = (o.y > 0.f) ? o.y : expm1f(o.y);
    o.z = (o.z > 0.f) ? o.z : expm1f(o.z);
    o.w = (o.w > 0.f) ? o.w : expm1f(o.w);
    pA1[i] = o;
  }
}

__global__ void k_fbeta(const float* __restrict__ Ssum,
                        const float* __restrict__ interatt,
                        float* __restrict__ fbetas) {
  int lane = threadIdx.x;  // 64 threads
  float invN = 1.f / (float)NN;
  float ia = interatt[lane];
  float d0 = wred(ia * Ssum[lane] * invN);
  float d1 = wred(ia * Ssum[64 + lane] * invN);
  float d2 = wred(ia * Ssum[128 + lane] * invN);
  float mm = fmaxf(fmaxf(d0, d1), d2);
  float e0 = expf(d0 - mm), e1 = expf(d1 - mm), e2 = expf(d2 - mm);
  float inv = 1.f / (e0 + e1 + e2);
  if (lane == 0) { fbetas[0] = e0 * inv; fbetas[1] = e1 * inv; fbetas[2] = e2 * inv; }
}

__global__ void __launch_bounds__(256) k_out(
    const float4* __restrict__ E0, const float4* __restrict__ E1,
    const float4* __restrict__ T, const float* __restrict__ fb,
    float4* __restrict__ out) {
  float b0 = fb[0], b1 = fb[1], b2 = fb[2];
  int total = NN * 64 / 4;
  for (int i = blockIdx.x * blockDim.x + threadIdx.x; i < total; i += gridDim.x * blockDim.x) {
    float4 a = E0[i], b = E1[i], c = T[i];
    float4 o;
    o.x = b0 * a.x + b1 * b.x + b2 * c.x;
    o.y = b0 * a.y + b1 * b.y + b2 * c.y;
    o.z = b0 * a.z + b1 * b.z + b2 * c.z;
    o.w = b0 * a.w + b1 * b.w + b2 * c.w;
    out[i] = o;
  }
}

extern "C" void kernel_launch(void* const* d_in, const int* in_sizes, int n_in,
                              void* d_out, int out_size, void* d_ws, size_t ws_size,
                              hipStream_t stream) {
  const float* target  = (const float*)d_in[0];
  const float* h0      = (const float*)d_in[1];
  const float* h1      = (const float*)d_in[2];
  const float* h2      = (const float*)d_in[3];
  const float* rf0     = (const float*)d_in[4];
  const float* rf1     = (const float*)d_in[5];
  const float* rf2     = (const float*)d_in[6];
  const int*   nei0    = (const int*)d_in[7];
  const int*   nei1    = (const int*)d_in[8];
  const float* att0    = (const float*)d_in[9];
  const float* att2_0  = (const float*)d_in[10];
  const float* Wr0     = (const float*)d_in[11];
  const float* br0     = (const float*)d_in[12];
  const float* Wr2_0   = (const float*)d_in[13];
  const float* br2_0   = (const float*)d_in[14];
  const float* aggW0   = (const float*)d_in[15];
  const float* aggb0   = (const float*)d_in[16];
  const float* aggatt0 = (const float*)d_in[17];
  const float* att1    = (const float*)d_in[18];
  const float* att2_1  = (const float*)d_in[19];
  const float* Wr1     = (const float*)d_in[20];
  const float* br1     = (const float*)d_in[21];
  const float* Wr2_1   = (const float*)d_in[22];
  const float* br2_1   = (const float*)d_in[23];
  const float* aggW1   = (const float*)d_in[24];
  const float* aggb1   = (const float*)d_in[25];
  const float* aggatt1 = (const float*)d_in[26];
  const float* interW  = (const float*)d_in[27];
  const float* interb  = (const float*)d_in[28];
  const float* interatt= (const float*)d_in[29];

  // ws: [0..447] atomic sums (s0A,s0R,s1A,s1R,S0,S1,S2), [448..451] ibetas,
  // [456..459] fbetas, [1024..) four e-arrays.
  float* ws = (float*)d_ws;
  float* sums   = ws;
  float* S012   = ws + 256;
  float* ibetas = ws + 448;
  float* fbetas = ws + 456;
  size_t EL = (size_t)NN * 64;
  float* eA0 = ws + 1024;
  float* eR0 = eA0 + EL;
  float* eA1 = eR0 + EL;
  float* eR1 = eA1 + EL;

  // scratch pairs live in d_out (8MB of 25.6MB; k_out rewrites all of d_out at the end)
  float* ob = (float*)d_out;
  float2* tp0a = (float2*)(ob);
  float2* tp0r = (float2*)(ob + 400000);
  float2* tp1a = (float2*)(ob + 800000);
  float2* tp1r = (float2*)(ob + 1000000);
  float2* np0a = (float2*)(ob + 1200000);
  float2* np0r = (float2*)(ob + 1400000);
  float2* np1a = (float2*)(ob + 1600000);
  float2* np1r = (float2*)(ob + 1800000);

  k_zero<<<2, 256, 0, stream>>>(ws);
  k_tab_pairs<<<782, 256, 0, stream>>>(h1,  att0   + 64, tp0a, M1);
  k_tab_pairs<<<782, 256, 0, stream>>>(rf1, att2_0 + 64, tp0r, M1);
  k_tab_pairs<<<391, 256, 0, stream>>>(h2,  att1   + 64, tp1a, M2);
  k_tab_pairs<<<391, 256, 0, stream>>>(rf2, att2_1 + 64, tp1r, M2);
  // segs: 0 -> (Wr0,br0,att0)@h0 -> np0a ; 1 -> (Wr1,br1,att1)@h0 -> np1a ;
  //       2 -> (Wr2_0,...)@rf0 -> np0r ; 3 -> (Wr2_1,...)@rf0 -> np1r
  k_node_pairs4<<<1564, 256, 0, stream>>>(h0, rf0,
      Wr0, br0, att0,  Wr1, br1, att1,
      Wr2_0, br2_0, att2_0,  Wr2_1, br2_1, att2_1,
      np0a, np1a, np0r, np1r);
  k_attend<<<2048, 256, 0, stream>>>(nei0, h1, rf1, tp0a, tp0r, np0a, np0r, eA0, eR0);
  k_attend<<<2048, 256, 0, stream>>>(nei1, h2, rf2, tp1a, tp1r, np1a, np1r, eA1, eR1);
  k_colsum_fast<<<391, 256, 0, stream>>>(eA0, aggW0, aggb0, sums + 0);
  k_colsum_fast<<<391, 256, 0, stream>>>(eR0, aggW0, aggb0, sums + 64);
  k_colsum_fast<<<391, 256, 0, stream>>>(eA1, aggW1, aggb1, sums + 128);
  k_colsum_fast<<<391, 256, 0, stream>>>(eR1, aggW1, aggb1, sums + 192);
  k_ibeta<<<1, 64, 0, stream>>>(sums, aggatt0, aggatt1, ibetas);
  k_mix_elem<<<2048, 256, 0, stream>>>((float4*)eA0, (const float4*)eR0,
                                       (float4*)eA1, (const float4*)eR1, ibetas);
  k_colsum_fast<<<391, 256, 0, stream>>>(eA0, interW, interb, S012 + 0);
  k_colsum_fast<<<391, 256, 0, stream>>>(eA1, interW, interb, S012 + 64);
  k_colsum_fast<<<391, 256, 0, stream>>>(target, interW, interb, S012 + 128);
  k_fbeta<<<1, 64, 0, stream>>>(S012, interatt, fbetas);
  k_out<<<2048, 256, 0, stream>>>((const float4*)eA0, (const float4*)eA1,
                                  (const float4*)target, fbetas, (float4*)d_out);
}

// Round 4
// 5524.872 us; speedup vs baseline: 1.5488x; 1.5488x over previous
//
#include <hip/hip_runtime.h>
#include <math.h>

#define NN 100000
#define M1 200000
#define M2 100000
#define TILES 1563  // ceil(NN/64)

__device__ __forceinline__ float bc(float x, int l) {
  return __int_as_float(__builtin_amdgcn_readlane(__float_as_int(x), l));
}

__device__ __forceinline__ float wred(float x) {
  x += __shfl_xor(x, 1, 64);
  x += __shfl_xor(x, 2, 64);
  x += __shfl_xor(x, 4, 64);
  x += __shfl_xor(x, 8, 64);
  x += __shfl_xor(x, 16, 64);
  x += __shfl_xor(x, 32, 64);
  return x;
}

// branch-free tanh: 1 - 2/(e^{2x}+1); saturates correctly at +-inf, ~1e-6 err.
__device__ __forceinline__ float tanh_fast(float x) {
  float e = __expf(2.f * x);
  return 1.f - 2.f / (e + 1.f);
}

__global__ void k_zero(float* p) { p[blockIdx.x * 256 + threadIdx.x] = 0.f; }

// ---- A1: per-table-row (dot = att_hi . row, asum = ||row||_1), all 4 tables fused ----
__global__ void __launch_bounds__(256) k_tab_pairs_all(
    const float* __restrict__ h1, const float* __restrict__ rf1,
    const float* __restrict__ h2, const float* __restrict__ rf2,
    const float* __restrict__ a0h, const float* __restrict__ a20h,
    const float* __restrict__ a1h, const float* __restrict__ a21h,
    float2* __restrict__ tp0a, float2* __restrict__ tp0r,
    float2* __restrict__ tp1a, float2* __restrict__ tp1r) {
  int r = blockIdx.x * 256 + threadIdx.x;  // [0, 600000)
  const float* tab; const float* att; float2* out; int rr;
  if (r < 200000)      { tab = h1;  att = a0h;  out = tp0a; rr = r; }
  else if (r < 400000) { tab = rf1; att = a20h; out = tp0r; rr = r - 200000; }
  else if (r < 500000) { tab = h2;  att = a1h;  out = tp1a; rr = r - 400000; }
  else if (r < 600000) { tab = rf2; att = a21h; out = tp1r; rr = r - 500000; }
  else return;
  const float4* row = (const float4*)(tab + (size_t)rr * 64);
  float dot = 0.f, asum = 0.f;
#pragma unroll
  for (int k = 0; k < 16; k++) {
    float4 v = row[k];
    float4 a = *(const float4*)(att + 4 * k);
    dot = fmaf(v.x, a.x, dot); dot = fmaf(v.y, a.y, dot);
    dot = fmaf(v.z, a.z, dot); dot = fmaf(v.w, a.w, dot);
    asum += fabsf(v.x) + fabsf(v.y) + fabsf(v.z) + fabsf(v.w);
  }
  out[rr] = make_float2(dot, asum);
}

// ---- A2: per-node pairs, 4-way split (seg = which of the 4 (W,b,att) combos) ----
__global__ void __launch_bounds__(256) k_node_pairs4(
    const float* __restrict__ h0, const float* __restrict__ rf0,
    const float* __restrict__ W0, const float* __restrict__ b0, const float* __restrict__ a0,
    const float* __restrict__ W1, const float* __restrict__ b1, const float* __restrict__ a1,
    const float* __restrict__ W2, const float* __restrict__ b2, const float* __restrict__ a2,
    const float* __restrict__ W3, const float* __restrict__ b3, const float* __restrict__ a3,
    float2* __restrict__ o0, float2* __restrict__ o1,
    float2* __restrict__ o2, float2* __restrict__ o3) {
  int seg = blockIdx.x & 3;
  int n = (blockIdx.x >> 2) * 256 + threadIdx.x;
  if (n >= NN) return;
  const float* X = (seg < 2) ? h0 : rf0;
  const float* W = (seg == 0) ? W0 : (seg == 1) ? W1 : (seg == 2) ? W2 : W3;
  const float* b = (seg == 0) ? b0 : (seg == 1) ? b1 : (seg == 2) ? b2 : b3;
  const float* a = (seg == 0) ? a0 : (seg == 1) ? a1 : (seg == 2) ? a2 : a3;
  float2* o      = (seg == 0) ? o0 : (seg == 1) ? o1 : (seg == 2) ? o2 : o3;

  float x[64];
  const float4* row = (const float4*)(X + (size_t)n * 64);
#pragma unroll
  for (int k = 0; k < 16; k++) {
    float4 v = row[k];
    x[4 * k] = v.x; x[4 * k + 1] = v.y; x[4 * k + 2] = v.z; x[4 * k + 3] = v.w;
  }
  float dot = 0.f, asum = 0.f;
  for (int d = 0; d < 64; d++) {  // rolled; W/b/a uniform -> scalar loads
    const float4* wr = (const float4*)(W + d * 64);
    float r0 = b[d], r1 = 0.f, r2 = 0.f, r3 = 0.f;
#pragma unroll
    for (int k = 0; k < 16; k += 4) {
      float4 wA = wr[k], wB = wr[k + 1], wC = wr[k + 2], wD = wr[k + 3];
      r0 = fmaf(wA.x, x[4*k+0],  r0); r0 = fmaf(wA.y, x[4*k+1],  r0);
      r0 = fmaf(wA.z, x[4*k+2],  r0); r0 = fmaf(wA.w, x[4*k+3],  r0);
      r1 = fmaf(wB.x, x[4*k+4],  r1); r1 = fmaf(wB.y, x[4*k+5],  r1);
      r1 = fmaf(wB.z, x[4*k+6],  r1); r1 = fmaf(wB.w, x[4*k+7],  r1);
      r2 = fmaf(wC.x, x[4*k+8],  r2); r2 = fmaf(wC.y, x[4*k+9],  r2);
      r2 = fmaf(wC.z, x[4*k+10], r2); r2 = fmaf(wC.w, x[4*k+11], r2);
      r3 = fmaf(wD.x, x[4*k+12], r3); r3 = fmaf(wD.y, x[4*k+13], r3);
      r3 = fmaf(wD.z, x[4*k+14], r3); r3 = fmaf(wD.w, x[4*k+15], r3);
    }
    float r = (r0 + r1) + (r2 + r3);
    dot = fmaf(a[d], r, dot);
    asum += fabsf(r);
  }
  o[n] = make_float2(dot, asum);
}

// ---- B: attend. wave = node, lane = dim. Scores on lanes 0..15, gathers coalesced. ----
__global__ void __launch_bounds__(256) k_attend(
    const int* __restrict__ nei,
    const float* __restrict__ tabA, const float* __restrict__ tabR,
    const float2* __restrict__ tpA, const float2* __restrict__ tpR,
    const float2* __restrict__ npA, const float2* __restrict__ npR,
    float* __restrict__ outA, float* __restrict__ outR) {
  int lane = threadIdx.x & 63, wid = threadIdx.x >> 6;
  for (int n = blockIdx.x * 4 + wid; n < NN; n += gridDim.x * 4) {
    const int* nb = nei + (size_t)n * 8;
    int myidx = nb[lane & 7];
    float2 pnA = npA[n], pnR = npR[n];           // uniform
    float2 pn = (lane & 8) ? pnR : pnA;
    const float2* tpp = (lane & 8) ? tpR : tpA;
    float2 tp = tpp[myidx];
    float t = (pn.x + tp.x) / fmaxf(pn.y + tp.y, 1e-12f);
    t = (t >= 0.f) ? t : 0.01f * t;              // leaky_relu(0.01)
    float m = t;
    m = fmaxf(m, __shfl_xor(m, 1, 64));
    m = fmaxf(m, __shfl_xor(m, 2, 64));
    m = fmaxf(m, __shfl_xor(m, 4, 64));
    float u = expf(t - m);
    float den = u;
    den += __shfl_xor(den, 1, 64);
    den += __shfl_xor(den, 2, 64);
    den += __shfl_xor(den, 4, 64);
    float w = u / den;                           // lanes 0..7: A weights, 8..15: R weights
    int is[8];
#pragma unroll
    for (int s = 0; s < 8; s++) is[s] = nb[s];   // uniform -> s_load
    float vA[8], vR[8];
#pragma unroll
    for (int s = 0; s < 8; s++) {
      vA[s] = tabA[(size_t)is[s] * 64 + lane];
      vR[s] = tabR[(size_t)is[s] * 64 + lane];
    }
    float eA = 0.f, eR = 0.f;
#pragma unroll
    for (int s = 0; s < 8; s++) {
      eA = fmaf(bc(w, s), vA[s], eA);
      eR = fmaf(bc(w, 8 + s), vR[s], eR);
    }
    outA[(size_t)n * 64 + lane] = eA;
    outR[(size_t)n * 64 + lane] = eR;
  }
}

// ---- C: out[d] += sum_n tanh(W[d,:].E[n,:] + b[d]).
// Block = 4 waves; wave wid owns dims [16*wid, 16*wid+16). lane = node.
// x[64] in VGPRs, acc[16] per lane (no spill), W rows via wave-uniform s_loads.
// seg-split grid fuses up to 4 (E,W,b,out) problems into one launch.
__global__ void __launch_bounds__(256) k_colsum4(
    const float* __restrict__ E0, const float* __restrict__ E1,
    const float* __restrict__ E2, const float* __restrict__ E3,
    const float* __restrict__ Wm0, const float* __restrict__ Wm1,
    const float* __restrict__ Wm2, const float* __restrict__ Wm3,
    const float* __restrict__ bb0, const float* __restrict__ bb1,
    const float* __restrict__ bb2, const float* __restrict__ bb3,
    float* __restrict__ ou0, float* __restrict__ ou1,
    float* __restrict__ ou2, float* __restrict__ ou3,
    int nseg, int ntg) {
  int seg = blockIdx.x % nseg;
  int tg  = blockIdx.x / nseg;
  const float* E = (seg == 0) ? E0 : (seg == 1) ? E1 : (seg == 2) ? E2 : E3;
  const float* W = (seg == 0) ? Wm0 : (seg == 1) ? Wm1 : (seg == 2) ? Wm2 : Wm3;
  const float* b = (seg == 0) ? bb0 : (seg == 1) ? bb1 : (seg == 2) ? bb2 : bb3;
  float* out     = (seg == 0) ? ou0 : (seg == 1) ? ou1 : (seg == 2) ? ou2 : ou3;
  int lane = threadIdx.x & 63, wid = threadIdx.x >> 6;
  const float* Wc = W + wid * 16 * 64;   // this wave's 16 rows
  const float* bc_ = b + wid * 16;
  float acc[16];
#pragma unroll
  for (int j = 0; j < 16; j++) acc[j] = 0.f;
  for (int t = tg; t < TILES; t += ntg) {
    int n = t * 64 + lane;
    bool valid = n < NN;
    const float4* row = (const float4*)(E + (size_t)(valid ? n : 0) * 64);
    float x[64];
#pragma unroll
    for (int k = 0; k < 16; k++) {
      float4 v = row[k];
      x[4 * k] = v.x; x[4 * k + 1] = v.y; x[4 * k + 2] = v.z; x[4 * k + 3] = v.w;
    }
    float vm = valid ? 1.f : 0.f;
#pragma unroll
    for (int j = 0; j < 16; j++) {
      const float4* wr = (const float4*)(Wc + j * 64);  // uniform -> s_load
      float r0 = bc_[j], r1 = 0.f, r2 = 0.f, r3 = 0.f;
#pragma unroll
      for (int k = 0; k < 16; k += 4) {
        float4 wA = wr[k], wB = wr[k + 1], wC = wr[k + 2], wD = wr[k + 3];
        r0 = fmaf(wA.x, x[4*k+0],  r0); r0 = fmaf(wA.y, x[4*k+1],  r0);
        r0 = fmaf(wA.z, x[4*k+2],  r0); r0 = fmaf(wA.w, x[4*k+3],  r0);
        r1 = fmaf(wB.x, x[4*k+4],  r1); r1 = fmaf(wB.y, x[4*k+5],  r1);
        r1 = fmaf(wB.z, x[4*k+6],  r1); r1 = fmaf(wB.w, x[4*k+7],  r1);
        r2 = fmaf(wC.x, x[4*k+8],  r2); r2 = fmaf(wC.y, x[4*k+9],  r2);
        r2 = fmaf(wC.z, x[4*k+10], r2); r2 = fmaf(wC.w, x[4*k+11], r2);
        r3 = fmaf(wD.x, x[4*k+12], r3); r3 = fmaf(wD.y, x[4*k+13], r3);
        r3 = fmaf(wD.z, x[4*k+14], r3); r3 = fmaf(wD.w, x[4*k+15], r3);
      }
      float r = (r0 + r1) + (r2 + r3);
      acc[j] += vm * tanh_fast(r);
    }
  }
  float keep = 0.f;
#pragma unroll
  for (int j = 0; j < 16; j++) {
    float s = wred(acc[j]);
    if (lane == j) keep = s;
  }
  if (lane < 16) atomicAdd(&out[wid * 16 + lane], keep);
}

__global__ void k_ibeta(const float* __restrict__ sums,
                        const float* __restrict__ aggatt0,
                        const float* __restrict__ aggatt1,
                        float* __restrict__ betas) {
  int lane = threadIdx.x;  // 64 threads
  float invN = 1.f / (float)NN;
#pragma unroll
  for (int r = 0; r < 2; r++) {
    const float* aggatt = r ? aggatt1 : aggatt0;
    float ga = wred(aggatt[lane] * sums[r * 128 + lane] * invN);
    float gb = wred(aggatt[lane] * sums[r * 128 + 64 + lane] * invN);
    float mm = fmaxf(ga, gb);
    float ea = expf(ga - mm), eb = expf(gb - mm);
    if (lane == 0) {
      betas[2 * r] = ea / (ea + eb);
      betas[2 * r + 1] = eb / (ea + eb);
    }
  }
}

__global__ void __launch_bounds__(256) k_mix_elem(
    float4* __restrict__ pA0, const float4* __restrict__ pR0,
    float4* __restrict__ pA1, const float4* __restrict__ pR1,
    const float* __restrict__ betas) {
  float ba0 = betas[0], bb0 = betas[1], ba1 = betas[2], bb1 = betas[3];
  int total = NN * 64 / 4;
  for (int i = blockIdx.x * blockDim.x + threadIdx.x; i < total; i += gridDim.x * blockDim.x) {
    float4 a = pA0[i], b = pR0[i];
    float4 o;
    o.x = ba0 * a.x + bb0 * b.x; o.y = ba0 * a.y + bb0 * b.y;
    o.z = ba0 * a.z + bb0 * b.z; o.w = ba0 * a.w + bb0 * b.w;
    o.x = (o.x > 0.f) ? o.x : expm1f(o.x);
    o.y = (o.y > 0.f) ? o.y : expm1f(o.y);
    o.z = (o.z > 0.f) ? o.z : expm1f(o.z);
    o.w = (o.w > 0.f) ? o.w : expm1f(o.w);
    pA0[i] = o;
    a = pA1[i]; b = pR1[i];
    o.x = ba1 * a.x + bb1 * b.x; o.y = ba1 * a.y + bb1 * b.y;
    o.z = ba1 * a.z + bb1 * b.z; o.w = ba1 * a.w + bb1 * b.w;
    o.x = (o.x > 0.f) ? o.x : expm1f(o.x);
    o.y = (o.y > 0.f) ? o.y : expm1f(o.y);
    o.z = (o.z > 0.f) ? o.z : expm1f(o.z);
    o.w = (o.w > 0.f) ? o.w : expm1f(o.w);
    pA1[i] = o;
  }
}

__global__ void k_fbeta(const float* __restrict__ Ssum,
                        const float* __restrict__ interatt,
                        float* __restrict__ fbetas) {
  int lane = threadIdx.x;  // 64 threads
  float invN = 1.f / (float)NN;
  float ia = interatt[lane];
  float d0 = wred(ia * Ssum[lane] * invN);
  float d1 = wred(ia * Ssum[64 + lane] * invN);
  float d2 = wred(ia * Ssum[128 + lane] * invN);
  float mm = fmaxf(fmaxf(d0, d1), d2);
  float e0 = expf(d0 - mm), e1 = expf(d1 - mm), e2 = expf(d2 - mm);
  float inv = 1.f / (e0 + e1 + e2);
  if (lane == 0) { fbetas[0] = e0 * inv; fbetas[1] = e1 * inv; fbetas[2] = e2 * inv; }
}

__global__ void __launch_bounds__(256) k_out(
    const float4* __restrict__ E0, const float4* __restrict__ E1,
    const float4* __restrict__ T, const float* __restrict__ fb,
    float4* __restrict__ out) {
  float b0 = fb[0], b1 = fb[1], b2 = fb[2];
  int total = NN * 64 / 4;
  for (int i = blockIdx.x * blockDim.x + threadIdx.x; i < total; i += gridDim.x * blockDim.x) {
    float4 a = E0[i], b = E1[i], c = T[i];
    float4 o;
    o.x = b0 * a.x + b1 * b.x + b2 * c.x;
    o.y = b0 * a.y + b1 * b.y + b2 * c.y;
    o.z = b0 * a.z + b1 * b.z + b2 * c.z;
    o.w = b0 * a.w + b1 * b.w + b2 * c.w;
    out[i] = o;
  }
}

extern "C" void kernel_launch(void* const* d_in, const int* in_sizes, int n_in,
                              void* d_out, int out_size, void* d_ws, size_t ws_size,
                              hipStream_t stream) {
  const float* target  = (const float*)d_in[0];
  const float* h0      = (const float*)d_in[1];
  const float* h1      = (const float*)d_in[2];
  const float* h2      = (const float*)d_in[3];
  const float* rf0     = (const float*)d_in[4];
  const float* rf1     = (const float*)d_in[5];
  const float* rf2     = (const float*)d_in[6];
  const int*   nei0    = (const int*)d_in[7];
  const int*   nei1    = (const int*)d_in[8];
  const float* att0    = (const float*)d_in[9];
  const float* att2_0  = (const float*)d_in[10];
  const float* Wr0     = (const float*)d_in[11];
  const float* br0     = (const float*)d_in[12];
  const float* Wr2_0   = (const float*)d_in[13];
  const float* br2_0   = (const float*)d_in[14];
  const float* aggW0   = (const float*)d_in[15];
  const float* aggb0   = (const float*)d_in[16];
  const float* aggatt0 = (const float*)d_in[17];
  const float* att1    = (const float*)d_in[18];
  const float* att2_1  = (const float*)d_in[19];
  const float* Wr1     = (const float*)d_in[20];
  const float* br1     = (const float*)d_in[21];
  const float* Wr2_1   = (const float*)d_in[22];
  const float* br2_1   = (const float*)d_in[23];
  const float* aggW1   = (const float*)d_in[24];
  const float* aggb1   = (const float*)d_in[25];
  const float* aggatt1 = (const float*)d_in[26];
  const float* interW  = (const float*)d_in[27];
  const float* interb  = (const float*)d_in[28];
  const float* interatt= (const float*)d_in[29];

  // ws: [0..447] atomic sums (s0A,s0R,s1A,s1R,S0,S1,S2), [448..451] ibetas,
  // [456..459] fbetas, [1024..) four e-arrays.
  float* ws = (float*)d_ws;
  float* sums   = ws;
  float* S012   = ws + 256;
  float* ibetas = ws + 448;
  float* fbetas = ws + 456;
  size_t EL = (size_t)NN * 64;
  float* eA0 = ws + 1024;
  float* eR0 = eA0 + EL;
  float* eA1 = eR0 + EL;
  float* eR1 = eA1 + EL;

  // scratch pairs live in d_out (8MB of 25.6MB; k_out rewrites all of d_out at the end)
  float* ob = (float*)d_out;
  float2* tp0a = (float2*)(ob);
  float2* tp0r = (float2*)(ob + 400000);
  float2* tp1a = (float2*)(ob + 800000);
  float2* tp1r = (float2*)(ob + 1000000);
  float2* np0a = (float2*)(ob + 1200000);
  float2* np0r = (float2*)(ob + 1400000);
  float2* np1a = (float2*)(ob + 1600000);
  float2* np1r = (float2*)(ob + 1800000);

  k_zero<<<2, 256, 0, stream>>>(ws);
  k_tab_pairs_all<<<2344, 256, 0, stream>>>(h1, rf1, h2, rf2,
      att0 + 64, att2_0 + 64, att1 + 64, att2_1 + 64,
      tp0a, tp0r, tp1a, tp1r);
  // segs: 0 -> (Wr0,br0,att0)@h0 -> np0a ; 1 -> (Wr1,br1,att1)@h0 -> np1a ;
  //       2 -> (Wr2_0,...)@rf0 -> np0r ; 3 -> (Wr2_1,...)@rf0 -> np1r
  k_node_pairs4<<<1564, 256, 0, stream>>>(h0, rf0,
      Wr0, br0, att0,  Wr1, br1, att1,
      Wr2_0, br2_0, att2_0,  Wr2_1, br2_1, att2_1,
      np0a, np1a, np0r, np1r);
  k_attend<<<2048, 256, 0, stream>>>(nei0, h1, rf1, tp0a, tp0r, np0a, np0r, eA0, eR0);
  k_attend<<<2048, 256, 0, stream>>>(nei1, h2, rf2, tp1a, tp1r, np1a, np1r, eA1, eR1);
  // agg colsums: 4 segs x 512 tile-groups = 2048 blocks
  k_colsum4<<<4 * 512, 256, 0, stream>>>(
      eA0, eR0, eA1, eR1,
      aggW0, aggW0, aggW1, aggW1,
      aggb0, aggb0, aggb1, aggb1,
      sums + 0, sums + 64, sums + 128, sums + 192,
      4, 512);
  k_ibeta<<<1, 64, 0, stream>>>(sums, aggatt0, aggatt1, ibetas);
  k_mix_elem<<<2048, 256, 0, stream>>>((float4*)eA0, (const float4*)eR0,
                                       (float4*)eA1, (const float4*)eR1, ibetas);
  // inter colsums: 3 segs x 683 tile-groups = 2049 blocks
  k_colsum4<<<3 * 683, 256, 0, stream>>>(
      eA0, eA1, target, target,
      interW, interW, interW, interW,
      interb, interb, interb, interb,
      S012 + 0, S012 + 64, S012 + 128, S012 + 128,
      3, 683);
  k_fbeta<<<1, 64, 0, stream>>>(S012, interatt, fbetas);
  k_out<<<2048, 256, 0, stream>>>((const float4*)eA0, (const float4*)eA1,
                                  (const float4*)target, fbetas, (float4*)d_out);
}